// Round 1
// baseline (460.996 us; speedup 1.0000x reference)
//
#include <hip/hip_runtime.h>
#include <hip/hip_bf16.h>

#define T_TOK 16384
#define E_EXP 16
#define CAP   2048
#define D_DIM 2048

// Kernel A: per-expert column cumsum of hot_mask, build slot->token inversion
// (src_tok, gate) in workspace, write loads (as float) into d_out tail.
// One block per expert (16 blocks x 256 threads).
__global__ __launch_bounds__(256) void scan_fill_kernel(
    const int*   __restrict__ hot_mask,   // [T, E]
    const float* __restrict__ score,      // [T, E]
    int*         __restrict__ src_tok,    // [E*CAP]
    float*       __restrict__ gate,       // [E*CAP]
    float*       __restrict__ loads_out)  // [E] (float-encoded ints)
{
    const int e   = blockIdx.x;
    const int tid = threadIdx.x;

    // sentinel-init this expert's slots (block owns the whole range)
    for (int s = tid; s < CAP; s += 256) src_tok[e * CAP + s] = T_TOK;

    __shared__ int wave_tot[4];
    __syncthreads();   // init visible before any fill writes

    const int lane = tid & 63;
    const int wv   = tid >> 6;
    int running = 0;

    for (int chunk = 0; chunk < T_TOK / 256; ++chunk) {
        const int t  = chunk * 256 + tid;
        const int hm = (hot_mask[t * E_EXP + e] > 0) ? 1 : 0;

        // inclusive scan within the 64-lane wave
        int incl = hm;
        #pragma unroll
        for (int off = 1; off < 64; off <<= 1) {
            int n = __shfl_up(incl, off, 64);
            if (lane >= off) incl += n;
        }
        if (lane == 63) wave_tot[wv] = incl;
        __syncthreads();

        int wave_off = 0;
        #pragma unroll
        for (int w = 0; w < 4; ++w) if (w < wv) wave_off += wave_tot[w];
        const int block_tot = wave_tot[0] + wave_tot[1] + wave_tot[2] + wave_tot[3];

        const int pos = running + wave_off + incl - 1;  // 0-based slot
        if (hm && pos < CAP) {
            src_tok[e * CAP + pos] = t;
            gate[e * CAP + pos]    = score[t * E_EXP + e];
        }
        running += block_tot;
        __syncthreads();   // wave_tot reused next chunk
    }

    if (tid == 0) {
        loads_out[e] = (float)(running < CAP ? running : CAP);
    }
}

// Kernel B: one block per output slot; copy scaled token row or zeros.
// D = 2048 floats = 512 float4; 256 threads x 2 float4 each.
__global__ __launch_bounds__(256) void gather_scale_kernel(
    const float* __restrict__ in_flow,   // [T, D]
    const int*   __restrict__ src_tok,   // [E*CAP]
    const float* __restrict__ gate,      // [E*CAP]
    float*       __restrict__ out)       // [E*CAP, D]
{
    const int slot = blockIdx.x;
    const int tid  = threadIdx.x;
    const int tok  = src_tok[slot];
    float4* orow = (float4*)(out + (size_t)slot * D_DIM);

    if (tok < T_TOK) {
        const float g = gate[slot];
        const float4* irow = (const float4*)(in_flow + (size_t)tok * D_DIM);
        float4 v0 = irow[tid];
        float4 v1 = irow[tid + 256];
        v0.x *= g; v0.y *= g; v0.z *= g; v0.w *= g;
        v1.x *= g; v1.y *= g; v1.z *= g; v1.w *= g;
        orow[tid]       = v0;
        orow[tid + 256] = v1;
    } else {
        float4 z = {0.f, 0.f, 0.f, 0.f};
        orow[tid]       = z;
        orow[tid + 256] = z;
    }
}

extern "C" void kernel_launch(void* const* d_in, const int* in_sizes, int n_in,
                              void* d_out, int out_size, void* d_ws, size_t ws_size,
                              hipStream_t stream) {
    const float* in_flow  = (const float*)d_in[0];
    const int*   hot_mask = (const int*)d_in[1];
    const float* score    = (const float*)d_in[2];

    float* out       = (float*)d_out;
    float* loads_out = out + (size_t)E_EXP * CAP * D_DIM;  // tail of d_out

    int*   src_tok = (int*)d_ws;                      // E*CAP ints  (128 KB)
    float* gate    = (float*)((char*)d_ws + E_EXP * CAP * sizeof(int));  // 128 KB

    scan_fill_kernel<<<E_EXP, 256, 0, stream>>>(hot_mask, score, src_tok, gate, loads_out);
    gather_scale_kernel<<<E_EXP * CAP, 256, 0, stream>>>(in_flow, src_tok, gate, out);
}

// Round 3
// 381.673 us; speedup vs baseline: 1.2078x; 1.2078x over previous
//
#include <hip/hip_runtime.h>
#include <hip/hip_bf16.h>

#define T_TOK 16384
#define E_EXP 16
#define CAP   2048
#define D_DIM 2048
#define NCHUNK (T_TOK / 256)   // 64 chunks of 256 tokens

typedef float vf4 __attribute__((ext_vector_type(4)));   // native vector for nontemporal builtins

// ---------- K1: per-chunk per-expert counts (64 blocks x 256 thr) ----------
__global__ __launch_bounds__(256) void count_kernel(
    const int* __restrict__ hot_mask,   // [T, E]
    int*       __restrict__ counts)     // [NCHUNK, E]
{
    const int chunk = blockIdx.x;
    const int tid   = threadIdx.x;
    const int t     = chunk * 256 + tid;
    const int lane  = tid & 63;
    const int wv    = tid >> 6;

    const int4* row = (const int4*)(hot_mask + (size_t)t * E_EXP);
    int4 r0 = row[0], r1 = row[1], r2 = row[2], r3 = row[3];
    int hm[16] = { r0.x > 0, r0.y > 0, r0.z > 0, r0.w > 0,
                   r1.x > 0, r1.y > 0, r1.z > 0, r1.w > 0,
                   r2.x > 0, r2.y > 0, r2.z > 0, r2.w > 0,
                   r3.x > 0, r3.y > 0, r3.z > 0, r3.w > 0 };

    __shared__ int wcnt[4][16];
    #pragma unroll
    for (int e = 0; e < 16; ++e) {
        unsigned long long m = __ballot(hm[e]);
        if (lane == 0) wcnt[wv][e] = __popcll(m);
    }
    __syncthreads();
    if (tid < 16)
        counts[chunk * E_EXP + tid] =
            wcnt[0][tid] + wcnt[1][tid] + wcnt[2][tid] + wcnt[3][tid];
}

// ---------- K2: scan chunk counts per expert (16 blocks x 64 thr) ----------
__global__ __launch_bounds__(64) void scan_kernel(
    const int* __restrict__ counts,      // [NCHUNK, E]
    int*       __restrict__ chunk_off,   // [NCHUNK, E] exclusive offsets
    int*       __restrict__ loads_i,     // [E] int
    float*     __restrict__ loads_out)   // [E] float (d_out tail)
{
    const int e    = blockIdx.x;
    const int lane = threadIdx.x;        // 0..63 == chunk id
    const int c    = counts[lane * E_EXP + e];
    int incl = c;
    #pragma unroll
    for (int off = 1; off < 64; off <<= 1) {
        int n = __shfl_up(incl, off, 64);
        if (lane >= off) incl += n;
    }
    chunk_off[lane * E_EXP + e] = incl - c;
    if (lane == 63) {
        int ld = incl < CAP ? incl : CAP;
        loads_i[e]   = ld;
        loads_out[e] = (float)ld;
    }
}

// ---------- K3: fill src_tok/gate for valid slots (64 blocks x 256 thr) ----
__global__ __launch_bounds__(256) void fill_kernel(
    const int*   __restrict__ hot_mask,
    const float* __restrict__ score,
    const int*   __restrict__ chunk_off,
    int*         __restrict__ src_tok,   // [E*CAP] (only valid slots written)
    float*       __restrict__ gate)      // [E*CAP]
{
    const int chunk = blockIdx.x;
    const int tid   = threadIdx.x;
    const int t     = chunk * 256 + tid;
    const int lane  = tid & 63;
    const int wv    = tid >> 6;

    const int4* mrow = (const int4*)(hot_mask + (size_t)t * E_EXP);
    int4 r0 = mrow[0], r1 = mrow[1], r2 = mrow[2], r3 = mrow[3];
    int hm[16] = { r0.x > 0, r0.y > 0, r0.z > 0, r0.w > 0,
                   r1.x > 0, r1.y > 0, r1.z > 0, r1.w > 0,
                   r2.x > 0, r2.y > 0, r2.z > 0, r2.w > 0,
                   r3.x > 0, r3.y > 0, r3.z > 0, r3.w > 0 };

    const float4* srow = (const float4*)(score + (size_t)t * E_EXP);
    float4 s0 = srow[0], s1 = srow[1], s2 = srow[2], s3 = srow[3];
    float sc[16] = { s0.x, s0.y, s0.z, s0.w, s1.x, s1.y, s1.z, s1.w,
                     s2.x, s2.y, s2.z, s2.w, s3.x, s3.y, s3.z, s3.w };

    __shared__ int wcnt[4][16];
    int before[16];
    const unsigned long long lmask = (1ULL << lane) - 1ULL;
    #pragma unroll
    for (int e = 0; e < 16; ++e) {
        unsigned long long m = __ballot(hm[e]);
        before[e] = __popcll(m & lmask);
        if (lane == 0) wcnt[wv][e] = __popcll(m);
    }
    __syncthreads();

    #pragma unroll
    for (int e = 0; e < 16; ++e) {
        if (hm[e]) {
            int woff = 0;
            for (int w = 0; w < 4; ++w) if (w < wv) woff += wcnt[w][e];
            const int pos = chunk_off[chunk * E_EXP + e] + woff + before[e];
            if (pos < CAP) {
                src_tok[e * CAP + pos] = t;
                gate[e * CAP + pos]    = sc[e];
            }
        }
    }
}

// ---------- K4: gather + scale (32768 blocks x 256 thr) --------------------
__global__ __launch_bounds__(256) void gather_scale_kernel(
    const float* __restrict__ in_flow,
    const int*   __restrict__ src_tok,
    const float* __restrict__ gate,
    const int*   __restrict__ loads_i,
    float*       __restrict__ out)
{
    const int slot = blockIdx.x;
    const int e    = slot >> 11;         // / CAP
    const int s    = slot & (CAP - 1);   // % CAP
    const int tid  = threadIdx.x;
    vf4* orow = (vf4*)(out + (size_t)slot * D_DIM);

    if (s < loads_i[e]) {
        const int   tok = src_tok[slot];
        const float g   = gate[slot];
        const vf4* irow = (const vf4*)(in_flow + (size_t)tok * D_DIM);
        vf4 v0 = irow[tid];
        vf4 v1 = irow[tid + 256];
        v0 *= g;
        v1 *= g;
        __builtin_nontemporal_store(v0, orow + tid);
        __builtin_nontemporal_store(v1, orow + tid + 256);
    } else {
        vf4 z = {0.f, 0.f, 0.f, 0.f};
        __builtin_nontemporal_store(z, orow + tid);
        __builtin_nontemporal_store(z, orow + tid + 256);
    }
}

extern "C" void kernel_launch(void* const* d_in, const int* in_sizes, int n_in,
                              void* d_out, int out_size, void* d_ws, size_t ws_size,
                              hipStream_t stream) {
    const float* in_flow  = (const float*)d_in[0];
    const int*   hot_mask = (const int*)d_in[1];
    const float* score    = (const float*)d_in[2];

    float* out       = (float*)d_out;
    float* loads_out = out + (size_t)E_EXP * CAP * D_DIM;

    char* ws = (char*)d_ws;
    int*   counts    = (int*)ws;                           ws += NCHUNK * E_EXP * sizeof(int);
    int*   chunk_off = (int*)ws;                           ws += NCHUNK * E_EXP * sizeof(int);
    int*   loads_i   = (int*)ws;                           ws += 64 * sizeof(int);
    int*   src_tok   = (int*)ws;                           ws += E_EXP * CAP * sizeof(int);
    float* gate      = (float*)ws;

    count_kernel<<<NCHUNK, 256, 0, stream>>>(hot_mask, counts);
    scan_kernel<<<E_EXP, 64, 0, stream>>>(counts, chunk_off, loads_i, loads_out);
    fill_kernel<<<NCHUNK, 256, 0, stream>>>(hot_mask, score, chunk_off, src_tok, gate);
    gather_scale_kernel<<<E_EXP * CAP, 256, 0, stream>>>(in_flow, src_tok, gate, loads_i, out);
}